// Round 1
// baseline (903.849 us; speedup 1.0000x reference)
//
#include <hip/hip_runtime.h>

// EntityMarker: inclusive span-mean over sequence_output rows.
//   sequence_output: [B, L, H] fp32, B=128, L=2048, H=768
//   entity_positions: [B, 4] int32 (h_start, h_end, t_start, t_end raw)
//   out: head [B,H] then tail [B,H], fp32, concatenated flat.
//
// v2: two-phase reduction, NO atomics, NO output memset.
//  Phase 1: each of 2B spans split into CHUNKS chunks for load balance
//           (span len 1..2048). Each block (192 thr, one float4 column per
//           thread) sums its chunk rows and writes the partial to
//           ws[span][chunk][H] with plain float4 stores. Empty chunks
//           write zeros, so ws needs no pre-clear.
//  Phase 2: one block per span sums the CHUNKS partials, scales by 1/len
//           once, writes every element of d_out (poison-proof without
//           memset).
// Rationale: v1's epilogue issued 3.1M device-scope fp32 atomicAdds with
// 16-way per-address contention scattered across all 8 XCDs (cross-XCD
// RMW serializes at the coherence point). Reads are only ~270 MB (~43 us
// at 6.3 TB/s); atomics were the structural excess.

#define L_SEQ  2048
#define H_DIM  768
#define CHUNKS 16
#define TPB    192   // H_DIM/4 float4 columns, 3 waves

// ---------------- Phase 1: per-chunk partial sums ----------------
__global__ __launch_bounds__(TPB) void span_partial_kernel(
    const float* __restrict__ seq,   // [B, L, H]
    const int*   __restrict__ pos,   // [B, 4]
    float*       __restrict__ ws,    // [2B, CHUNKS, H]
    int B)
{
    const int blk     = blockIdx.x;
    const int chunk   = blk % CHUNKS;
    const int span_id = blk / CHUNKS;     // 0 .. 2B-1
    const int ent     = span_id & 1;      // 0 = head, 1 = tail
    const int b       = span_id >> 1;

    const int p0 = pos[b * 4 + 2 * ent + 0];
    const int p1 = pos[b * 4 + 2 * ent + 1];
    const int s  = min(max(p0, 0), L_SEQ - 1);
    const int e  = max(s, min(p1, L_SEQ - 1));
    const int len = e - s + 1;            // >= 1

    // This chunk's row range [r0, r1) — may be empty; still write zeros.
    const int per = (len + CHUNKS - 1) / CHUNKS;
    const int r0  = s + chunk * per;
    const int r1  = min(r0 + per, e + 1);

    const int col = threadIdx.x;          // float4 column, 0..191
    const float4* __restrict__ base =
        (const float4*)(seq + (size_t)b * L_SEQ * H_DIM);

    float4 acc0 = make_float4(0.f, 0.f, 0.f, 0.f);
    float4 acc1 = make_float4(0.f, 0.f, 0.f, 0.f);
    int r = r0;
    for (; r + 1 < r1; r += 2) {
        float4 v0 = base[(size_t)r       * (H_DIM / 4) + col];
        float4 v1 = base[(size_t)(r + 1) * (H_DIM / 4) + col];
        acc0.x += v0.x; acc0.y += v0.y; acc0.z += v0.z; acc0.w += v0.w;
        acc1.x += v1.x; acc1.y += v1.y; acc1.z += v1.z; acc1.w += v1.w;
    }
    if (r < r1) {
        float4 v0 = base[(size_t)r * (H_DIM / 4) + col];
        acc0.x += v0.x; acc0.y += v0.y; acc0.z += v0.z; acc0.w += v0.w;
    }

    float4 res = make_float4(acc0.x + acc1.x, acc0.y + acc1.y,
                             acc0.z + acc1.z, acc0.w + acc1.w);
    float4* wsv = (float4*)ws;
    wsv[((size_t)span_id * CHUNKS + chunk) * (H_DIM / 4) + col] = res;
}

// ---------------- Phase 2: reduce partials, scale, store ----------------
__global__ __launch_bounds__(TPB) void span_reduce_kernel(
    const float* __restrict__ ws,    // [2B, CHUNKS, H]
    const int*   __restrict__ pos,   // [B, 4]
    float*       __restrict__ out,   // [2, B, H]
    int B)
{
    const int span_id = blockIdx.x;       // 0 .. 2B-1
    const int ent     = span_id & 1;
    const int b       = span_id >> 1;

    const int p0 = pos[b * 4 + 2 * ent + 0];
    const int p1 = pos[b * 4 + 2 * ent + 1];
    const int s  = min(max(p0, 0), L_SEQ - 1);
    const int e  = max(s, min(p1, L_SEQ - 1));
    const int len = e - s + 1;

    const int col = threadIdx.x;          // 0..191
    const float4* __restrict__ base =
        (const float4*)ws + (size_t)span_id * CHUNKS * (H_DIM / 4);

    float4 acc = make_float4(0.f, 0.f, 0.f, 0.f);
#pragma unroll
    for (int c = 0; c < CHUNKS; ++c) {
        float4 v = base[(size_t)c * (H_DIM / 4) + col];
        acc.x += v.x; acc.y += v.y; acc.z += v.z; acc.w += v.w;
    }

    const float inv = 1.0f / (float)len;
    float4 res = make_float4(acc.x * inv, acc.y * inv, acc.z * inv, acc.w * inv);
    float4* o = (float4*)(out + (size_t)ent * B * H_DIM + (size_t)b * H_DIM);
    o[col] = res;
}

// ---------------- Fallback (old v1 atomic path, used only if ws too small) ----------------
__global__ __launch_bounds__(TPB) void entity_span_mean_atomic_kernel(
    const float* __restrict__ seq,
    const int*   __restrict__ pos,
    float*       __restrict__ out,
    int B)
{
    const int blk     = blockIdx.x;
    const int chunk   = blk % CHUNKS;
    const int span_id = blk / CHUNKS;
    const int ent     = span_id & 1;
    const int b       = span_id >> 1;

    const int p0 = pos[b * 4 + 2 * ent + 0];
    const int p1 = pos[b * 4 + 2 * ent + 1];
    const int s  = min(max(p0, 0), L_SEQ - 1);
    const int e  = max(s, min(p1, L_SEQ - 1));
    const int len = e - s + 1;

    const int per = (len + CHUNKS - 1) / CHUNKS;
    const int r0  = s + chunk * per;
    const int r1  = min(r0 + per, e + 1);
    if (r0 >= r1) return;

    const int col = threadIdx.x;
    const float4* __restrict__ base =
        (const float4*)(seq + (size_t)b * L_SEQ * H_DIM);

    float4 acc0 = make_float4(0.f, 0.f, 0.f, 0.f);
    float4 acc1 = make_float4(0.f, 0.f, 0.f, 0.f);
    int r = r0;
    for (; r + 1 < r1; r += 2) {
        float4 v0 = base[(size_t)r       * (H_DIM / 4) + col];
        float4 v1 = base[(size_t)(r + 1) * (H_DIM / 4) + col];
        acc0.x += v0.x; acc0.y += v0.y; acc0.z += v0.z; acc0.w += v0.w;
        acc1.x += v1.x; acc1.y += v1.y; acc1.z += v1.z; acc1.w += v1.w;
    }
    if (r < r1) {
        float4 v0 = base[(size_t)r * (H_DIM / 4) + col];
        acc0.x += v0.x; acc0.y += v0.y; acc0.z += v0.z; acc0.w += v0.w;
    }

    const float inv = 1.0f / (float)len;
    float* o = out + (size_t)ent * B * H_DIM + (size_t)b * H_DIM + col * 4;
    atomicAdd(o + 0, (acc0.x + acc1.x) * inv);
    atomicAdd(o + 1, (acc0.y + acc1.y) * inv);
    atomicAdd(o + 2, (acc0.z + acc1.z) * inv);
    atomicAdd(o + 3, (acc0.w + acc1.w) * inv);
}

extern "C" void kernel_launch(void* const* d_in, const int* in_sizes, int n_in,
                              void* d_out, int out_size, void* d_ws, size_t ws_size,
                              hipStream_t stream) {
    const float* seq = (const float*)d_in[0];
    const int*   pos = (const int*)d_in[1];
    float*       out = (float*)d_out;

    const int B = in_sizes[1] / 4;        // 128

    const size_t ws_needed = (size_t)2 * B * CHUNKS * H_DIM * sizeof(float); // 12.6 MB

    if (d_ws != nullptr && ws_size >= ws_needed) {
        float* ws = (float*)d_ws;
        const int n_blocks = 2 * B * CHUNKS;  // 4096
        span_partial_kernel<<<n_blocks, TPB, 0, stream>>>(seq, pos, ws, B);
        span_reduce_kernel<<<2 * B, TPB, 0, stream>>>(ws, pos, out, B);
    } else {
        // Fallback: original atomic path (needs zeroed output).
        hipMemsetAsync(d_out, 0, (size_t)out_size * sizeof(float), stream);
        const int n_blocks = 2 * B * CHUNKS;
        entity_span_mean_atomic_kernel<<<n_blocks, TPB, 0, stream>>>(seq, pos, out, B);
    }
}